// Round 6
// baseline (710.391 us; speedup 1.0000x reference)
//
#include <hip/hip_runtime.h>
#include <hip/hip_bf16.h>
#include <math.h>

// Problem: input (16,1024,512) f32, codebook (8192,512) f32
#define N_ROWS 16384
#define DIM    512
#define VOCAB  8192

typedef __attribute__((ext_vector_type(8))) short short8;
typedef __attribute__((ext_vector_type(4))) float f32x4;

__device__ inline unsigned short f2bf(float f) {      // RNE f32 -> bf16 bits
    unsigned u = __float_as_uint(f);
    u += 0x7fff + ((u >> 16) & 1);
    return (unsigned short)(u >> 16);
}

__device__ inline void gload16(const void* g, void* l) {
    __builtin_amdgcn_global_load_lds(
        (const __attribute__((address_space(1))) void*)g,
        (__attribute__((address_space(3))) void*)l, 16, 0, 0);
}

// ---------------------------------------------------------------------------
// fp32 -> bf16 for input x (element-parallel)
// ---------------------------------------------------------------------------
__global__ void k_split_hi(const float* __restrict__ in, unsigned short* __restrict__ hi,
                           int n4) {
    int t = blockIdx.x * 256 + threadIdx.x;
    if (t >= n4) return;
    float4 v = reinterpret_cast<const float4*>(in)[t];
    ushort4 h;
    h.x = f2bf(v.x); h.y = f2bf(v.y); h.z = f2bf(v.z); h.w = f2bf(v.w);
    reinterpret_cast<ushort4*>(hi)[t] = h;
}

// ---------------------------------------------------------------------------
// codebook: fp32 -> bf16 AND c2[v] = sum(cb[v]^2) in one pass.
// One wave per row (512 floats = 8/lane), 4 waves/block.
// ---------------------------------------------------------------------------
__global__ void k_split_cb(const float* __restrict__ cb, unsigned short* __restrict__ hi,
                           float* __restrict__ c2) {
    int row  = blockIdx.x * 4 + (threadIdx.x >> 6);
    int lane = threadIdx.x & 63;
    const float4* p = reinterpret_cast<const float4*>(cb + (size_t)row * DIM);
    float4 a = p[lane * 2], b = p[lane * 2 + 1];
    float s = a.x*a.x + a.y*a.y + a.z*a.z + a.w*a.w
            + b.x*b.x + b.y*b.y + b.z*b.z + b.w*b.w;
    short8 h;
    h[0] = f2bf(a.x); h[1] = f2bf(a.y); h[2] = f2bf(a.z); h[3] = f2bf(a.w);
    h[4] = f2bf(b.x); h[5] = f2bf(b.y); h[6] = f2bf(b.z); h[7] = f2bf(b.w);
    *reinterpret_cast<short8*>(hi + (size_t)row * DIM + lane * 8) = h;
#pragma unroll
    for (int off = 32; off > 0; off >>= 1) s += __shfl_xor(s, off, 64);
    if (lane == 0) c2[row] = s;
}

// ---------------------------------------------------------------------------
// B-resident VQ GEMM + fused top-2 argmin.
// 256 persistent blocks (= 64 col-tiles x 4 row-slots), 512 threads (8 waves).
// Block stages its 128-col x K512 codebook tile in LDS ONCE (128 KB,
// XOR-swizzled, rule-21), one __syncthreads, then NO barriers: each wave
// computes 64 rows x 128 cols per row-group (acc[4][8]), looping 8 row-groups
// of 512 rows. A-fragments stream global->reg, double-buffered 1 K-step ahead.
// Per-tile top-2 + part[] layout identical to the validated round-2 path.
// ---------------------------------------------------------------------------
__launch_bounds__(512, 1)
__global__ void k_vq(const unsigned short* __restrict__ xhi,
                     const unsigned short* __restrict__ cbhi,
                     const float* __restrict__ c2,
                     float4* __restrict__ part) {
    __shared__ __align__(16) char Bs[131072];   // [128 cols][64 slots of 16B]
    const int tid  = threadIdx.x;
    const int w    = tid >> 6;
    const int lane = tid & 63;
    const int l15  = lane & 15;
    const int lg   = lane >> 4;

    const int c    = blockIdx.x & 63;        // col-tile id (128 codes)
    const int s    = blockIdx.x >> 6;        // row-slot 0..3
    const int colBase = c * 128;

    // --- stage B once: wave w stages cols w*16 .. w*16+15 (1024 B each) ---
    // LDS linear; source slot pre-XORed with (col&7) so swizzled reads are
    // linear-data (rule 21, involution).
#pragma unroll
    for (int t = 0; t < 16; ++t) {
        int col = w * 16 + t;
        gload16((const char*)cbhi + (size_t)(colBase + col) * 1024 +
                    ((lane << 4) ^ ((col & 7) << 4)),
                Bs + col * 1024);
    }
    __syncthreads();   // only block-wide sync in the kernel

    float c2v[8];
#pragma unroll
    for (int nj = 0; nj < 8; ++nj) c2v[nj] = c2[colBase + nj * 16 + l15];

    const char* xb   = (const char*)xhi;
    const int   bxor = (l15 & 7) << 4;       // B read swizzle mask (col&7 = l15&7)

#define LOADA(BUF, KS) do {                                                    \
    _Pragma("unroll") for (int mi = 0; mi < 4; ++mi)                           \
        af[BUF][mi] = *(const short8*)(xb + abase + (mi * 16 + l15) * 1024 +   \
                                       ((KS) * 4 + lg) * 16); } while (0)

    for (int rg = 0; rg < 8; ++rg) {
        const int rowg = s + 4 * rg;                     // row-group 0..31
        const int wrow = rowg * 512 + w * 64;            // wave's first row
        const size_t abase = (size_t)wrow * 1024;

        f32x4 acc[4][8];
#pragma unroll
        for (int mi = 0; mi < 4; ++mi)
#pragma unroll
            for (int nj = 0; nj < 8; ++nj) acc[mi][nj] = (f32x4)0.f;

        short8 af[2][4];
        LOADA(0, 0);
#pragma unroll
        for (int ks = 0; ks < 16; ++ks) {                // 16 K-steps of 32
            const int cur = ks & 1;
            if (ks < 15) LOADA(cur ^ 1, ks + 1);         // prefetch next
            short8 bf[8];
#pragma unroll
            for (int nj = 0; nj < 8; ++nj) {
                int col  = nj * 16 + l15;
                int slot = ks * 4 + lg;
                bf[nj] = *(const short8*)(Bs + col * 1024 + ((slot << 4) ^ bxor));
            }
#pragma unroll
            for (int mi = 0; mi < 4; ++mi)
#pragma unroll
                for (int nj = 0; nj < 8; ++nj)
                    acc[mi][nj] = __builtin_amdgcn_mfma_f32_16x16x32_bf16(
                        af[cur][mi], bf[nj], acc[mi][nj], 0, 0, 0);
        }

        // Epilogue: score = c2 - 2*dot; top-2 per row over 128 cols.
        // C layout (m89): col = l15, row = 4*lg + reg (+ mi*16 + wrow).
#pragma unroll
        for (int mi = 0; mi < 4; ++mi) {
#pragma unroll
            for (int reg = 0; reg < 4; ++reg) {
                float s1 = INFINITY, s2 = INFINITY;
                int   i1 = 0x7fffffff, i2 = 0x7fffffff;
#pragma unroll
                for (int nj = 0; nj < 8; ++nj) {
                    float sc = fmaf(-2.f, acc[mi][nj][reg], c2v[nj]);
                    int   v  = colBase + nj * 16 + l15;
                    if (sc < s1 || (sc == s1 && v < i1)) { s2 = s1; i2 = i1; s1 = sc; i1 = v; }
                    else if (sc < s2 || (sc == s2 && v < i2)) { s2 = sc; i2 = v; }
                }
#pragma unroll
                for (int off = 1; off < 16; off <<= 1) {   // butterfly, 16 col-lanes
                    float t1 = __shfl_xor(s1, off, 64); int j1 = __shfl_xor(i1, off, 64);
                    float t2 = __shfl_xor(s2, off, 64); int j2 = __shfl_xor(i2, off, 64);
                    bool bfirst = (t1 < s1) || (t1 == s1 && j1 < i1);
                    if (bfirst) {
                        float ns; int ni;
                        if (s1 < t2 || (s1 == t2 && i1 < j2)) { ns = s1; ni = i1; }
                        else                                   { ns = t2; ni = j2; }
                        s1 = t1; i1 = j1; s2 = ns; i2 = ni;
                    } else if (t1 < s2 || (t1 == s2 && j1 < i2)) { s2 = t1; i2 = j1; }
                }
                if (l15 == 0) {
                    int row = wrow + mi * 16 + 4 * lg + reg;
                    part[(size_t)row * 64 + c] =
                        make_float4(s1, __int_as_float(i1), s2, __int_as_float(i2));
                }
            }
        }
    }
#undef LOADA
}

// ---------------------------------------------------------------------------
// Per-row final: approx global min over 64 tile-top2s; exact fp32 rescore of
// every candidate within min+1.0 (>14 sigma of bf16 approx error);
// lexicographic (score, idx) min == reference argmin semantics.
// ---------------------------------------------------------------------------
__global__ void k_select(const float4* __restrict__ part,
                         const float* __restrict__ x,
                         const float* __restrict__ cb,
                         const float* __restrict__ c2,
                         float* __restrict__ out_idx_f,
                         int* __restrict__ idx_i,
                         int* __restrict__ used) {
    int wv   = threadIdx.x >> 6;
    int lane = threadIdx.x & 63;
    int row  = blockIdx.x * 4 + wv;
    float4 p = part[(size_t)row * 64 + lane];
    float s1 = p.x; int i1 = __float_as_int(p.y);
    float s2 = p.z; int i2 = __float_as_int(p.w);
    float gm = s1;
#pragma unroll
    for (int off = 1; off < 64; off <<= 1) gm = fminf(gm, __shfl_xor(gm, off, 64));
    float thresh = gm + 1.0f;
    unsigned long long m1 = __ballot(s1 <= thresh);
    unsigned long long m2 = __ballot(s2 <= thresh);
    float be = INFINITY; int bi = 0x7fffffff;
    const float4* xr = reinterpret_cast<const float4*>(x + (size_t)row * DIM);
    while (m1 | m2) {
        int vi;
        if (m1) { int t = __ffsll(m1) - 1; m1 &= m1 - 1; vi = __shfl(i1, t); }
        else    { int t = __ffsll(m2) - 1; m2 &= m2 - 1; vi = __shfl(i2, t); }
        const float4* cr = reinterpret_cast<const float4*>(cb + (size_t)vi * DIM);
        float d = 0.f;
#pragma unroll
        for (int q = 0; q < 2; ++q) {
            float4 a = xr[q * 64 + lane];
            float4 b = cr[q * 64 + lane];
            d += a.x * b.x + a.y * b.y + a.z * b.z + a.w * b.w;
        }
#pragma unroll
        for (int off = 1; off < 64; off <<= 1) d += __shfl_xor(d, off, 64);
        float se = c2[vi] - 2.f * d;
        if (se < be || (se == be && vi < bi)) { be = se; bi = vi; }
    }
    if (lane == 0) {
        out_idx_f[row] = (float)bi;
        idx_i[row]     = bi;
        used[bi]       = 1;
    }
}

__global__ void k_streak(const int* __restrict__ streak_in,
                         const int* __restrict__ used,
                         float* __restrict__ out) {
    int v = blockIdx.x * 256 + threadIdx.x;
    if (v < VOCAB) out[v] = used[v] ? 0.f : (float)(streak_in[v] + 1);
}

__global__ void k_gather(const float* __restrict__ cb,
                         const int* __restrict__ idx_i,
                         float* __restrict__ out) {
    size_t t  = (size_t)blockIdx.x * 256 + threadIdx.x;
    int    n  = (int)(t >> 7);
    int    d4 = (int)(t & 127);
    reinterpret_cast<float4*>(out)[t] =
        reinterpret_cast<const float4*>(cb + (size_t)idx_i[n] * DIM)[d4];
}

extern "C" void kernel_launch(void* const* d_in, const int* in_sizes, int n_in,
                              void* d_out, int out_size, void* d_ws, size_t ws_size,
                              hipStream_t stream) {
    const float* x      = (const float*)d_in[0];
    const float* cb     = (const float*)d_in[1];
    const int*   streak = (const int*)d_in[2];

    float* out       = (float*)d_out;
    float* out_embed = out;
    float* out_idx   = out + (size_t)N_ROWS * DIM;
    float* out_strk  = out_idx + N_ROWS;

    char* ws = (char*)d_ws;
    unsigned short* xhi  = (unsigned short*)(ws);                 // 16.8 MB
    unsigned short* cbhi = (unsigned short*)(ws + (32u << 20));   // 8.4 MB
    float* c2    = (float*)(ws + (48u << 20));                    // 32 KB
    int*   idx_i = (int*)(ws + (48u << 20) + (1u << 16));         // 64 KB
    int*   used  = (int*)(ws + (48u << 20) + (2u << 16));         // 32 KB
    float4* part = (float4*)(ws + (49u << 20));                   // 16.8 MB

    hipMemsetAsync(used, 0, VOCAB * sizeof(int), stream);
    k_split_hi<<<(N_ROWS * DIM / 4) / 256, 256, 0, stream>>>(x, xhi, N_ROWS * DIM / 4);
    k_split_cb<<<VOCAB / 4, 256, 0, stream>>>(cb, cbhi, c2);
    k_vq<<<256, 512, 0, stream>>>(xhi, cbhi, c2, part);
    k_select<<<N_ROWS / 4, 256, 0, stream>>>(part, x, cb, c2, out_idx, idx_i, used);
    k_streak<<<VOCAB / 256, 256, 0, stream>>>(streak, used, out_strk);
    k_gather<<<(N_ROWS * DIM / 4) / 256, 256, 0, stream>>>(cb, idx_i, out_embed);
}

// Round 7
// 464.803 us; speedup vs baseline: 1.5284x; 1.5284x over previous
//
#include <hip/hip_runtime.h>
#include <hip/hip_bf16.h>
#include <math.h>

// Problem: input (16,1024,512) f32, codebook (8192,512) f32
#define N_ROWS 16384
#define DIM    512
#define VOCAB  8192

typedef __attribute__((ext_vector_type(8))) short short8;
typedef __attribute__((ext_vector_type(4))) float f32x4;

__device__ inline unsigned short f2bf(float f) {      // RNE f32 -> bf16 bits
    unsigned u = __float_as_uint(f);
    u += 0x7fff + ((u >> 16) & 1);
    return (unsigned short)(u >> 16);
}

__device__ inline void gload16(const void* g, void* l) {
    __builtin_amdgcn_global_load_lds(
        (const __attribute__((address_space(1))) void*)g,
        (__attribute__((address_space(3))) void*)l, 16, 0, 0);
}

// ---------------------------------------------------------------------------
// fp32 -> bf16 for input x
// ---------------------------------------------------------------------------
__global__ void k_split_hi(const float* __restrict__ in, unsigned short* __restrict__ hi,
                           int n4) {
    int t = blockIdx.x * 256 + threadIdx.x;
    if (t >= n4) return;
    float4 v = reinterpret_cast<const float4*>(in)[t];
    ushort4 h;
    h.x = f2bf(v.x); h.y = f2bf(v.y); h.z = f2bf(v.z); h.w = f2bf(v.w);
    reinterpret_cast<ushort4*>(hi)[t] = h;
}

// ---------------------------------------------------------------------------
// codebook: fp32 -> bf16 AND c2[v] = sum(cb[v]^2) in one pass (validated r6)
// ---------------------------------------------------------------------------
__global__ void k_split_cb(const float* __restrict__ cb, unsigned short* __restrict__ hi,
                           float* __restrict__ c2) {
    int row  = blockIdx.x * 4 + (threadIdx.x >> 6);
    int lane = threadIdx.x & 63;
    const float4* p = reinterpret_cast<const float4*>(cb + (size_t)row * DIM);
    float4 a = p[lane * 2], b = p[lane * 2 + 1];
    float s = a.x*a.x + a.y*a.y + a.z*a.z + a.w*a.w
            + b.x*b.x + b.y*b.y + b.z*b.z + b.w*b.w;
    short8 h;
    h[0] = f2bf(a.x); h[1] = f2bf(a.y); h[2] = f2bf(a.z); h[3] = f2bf(a.w);
    h[4] = f2bf(b.x); h[5] = f2bf(b.y); h[6] = f2bf(b.z); h[7] = f2bf(b.w);
    *reinterpret_cast<short8*>(hi + (size_t)row * DIM + lane * 8) = h;
#pragma unroll
    for (int off = 32; off > 0; off >>= 1) s += __shfl_xor(s, off, 64);
    if (lane == 0) c2[row] = s;
}

// ---------------------------------------------------------------------------
// A-resident VQ GEMM + in-register running top-2 argmin.
// Grid = 256 blocks (1/CU): block = (row-tile rt of 128 rows, col-half h of
// 4096 cols). LDS: A panel [64 kslot][128 row][16B] = 128 KB staged ONCE;
// B ring 3 x [4 kslot][128 col][16B] = 24 KB, streamed 8 KB/step (BK=32),
// counted vmcnt(1) (2-step prefetch). All LDS layouts kslot-major ->
// lane-contiguous reads/writes, conflict-free, no swizzle.
// 8 waves = 4M x 2N: wave = 32 rows x 64 cols, acc[2][4] (32 AGPR).
// Top-2 kept per thread across all 32 col-tiles; one butterfly at the end.
// part[row][4]: entry e = h*2+wn holds top-2 of that 2048-col span.
// ---------------------------------------------------------------------------
__launch_bounds__(512, 2)
__global__ void k_vq(const unsigned short* __restrict__ xhi,
                     const unsigned short* __restrict__ cbhi,
                     const float* __restrict__ c2,
                     float4* __restrict__ part) {
    __shared__ __align__(16) char Ar[131072];   // [64 ks][128 row][16B]
    __shared__ __align__(16) char Br[24576];    // 3 x [4 ks][128 col][16B]
    const int tid  = threadIdx.x;
    const int w    = tid >> 6;
    const int lane = tid & 63;
    const int l15  = lane & 15;
    const int lg   = lane >> 4;
    const int wm   = w >> 1;            // 0..3 : 32-row group
    const int wn   = w & 1;             // 0..1 : 64-col group

    const int h       = blockIdx.x & 1;
    const int rt      = blockIdx.x >> 1;
    const int rowBase = rt * 128;
    const int colBase = h * 4096;

    const char* xb  = (const char*)xhi;
    const char* cbb = (const char*)cbhi;

    // ---- prologue: A panel (16 gload16/thread) + B steps 0,1 ----
#pragma unroll
    for (int j = 0; j < 16; ++j) {
        int unit = j * 512 + tid;              // = kslot*128 + row
        int ks = unit >> 7, r = unit & 127;
        gload16(xb + (size_t)(rowBase + r) * 1024 + ks * 16, Ar + unit * 16);
    }
    const int sB = tid >> 7, cB = tid & 127;   // B staging coords (ks, col)
    gload16(cbb + (size_t)(colBase + cB) * 1024 + 0  + sB * 16, Br + tid * 16);
    gload16(cbb + (size_t)(colBase + cB) * 1024 + 64 + sB * 16, Br + 8192 + tid * 16);
    asm volatile("s_waitcnt vmcnt(1)" ::: "memory");   // A + B(0) landed
    __builtin_amdgcn_s_barrier();

    f32x4 acc[2][4];
    float bs1[2][4], bs2[2][4];
    int   bi1[2][4], bi2[2][4];
#pragma unroll
    for (int mi = 0; mi < 2; ++mi)
#pragma unroll
        for (int r = 0; r < 4; ++r) {
            bs1[mi][r] = INFINITY;  bs2[mi][r] = INFINITY;
            bi1[mi][r] = 0x7fffffff; bi2[mi][r] = 0x7fffffff;
        }

    int bcur = 0;                               // = t % 3 (ring index)
    for (int t = 0; t < 512; ++t) {             // t = ct*16 + kt
        if (t < 510) {                          // stage B(t+2) into ring
            int t2 = t + 2;
            int bn = bcur + 2; if (bn >= 3) bn -= 3;
            gload16(cbb + (size_t)(colBase + (t2 >> 4) * 128 + cB) * 1024
                        + (t2 & 15) * 64 + sB * 16,
                    Br + bn * 8192 + tid * 16);
        }
        __builtin_amdgcn_sched_barrier(0);      // keep stage issued first

        const int ct = t >> 4, kt = t & 15;
        if (kt == 0) {
#pragma unroll
            for (int mi = 0; mi < 2; ++mi)
#pragma unroll
                for (int nj = 0; nj < 4; ++nj) acc[mi][nj] = (f32x4)0.f;
        }
        const char* Bb = Br + bcur * 8192;
        short8 a[2], b[4];
#pragma unroll
        for (int mi = 0; mi < 2; ++mi)
            a[mi] = *(const short8*)(Ar +
                     (((kt * 4 + lg) * 128) + wm * 32 + mi * 16 + l15) * 16);
#pragma unroll
        for (int nj = 0; nj < 4; ++nj)
            b[nj] = *(const short8*)(Bb +
                     ((lg * 128) + wn * 64 + nj * 16 + l15) * 16);
#pragma unroll
        for (int mi = 0; mi < 2; ++mi)
#pragma unroll
            for (int nj = 0; nj < 4; ++nj)
                acc[mi][nj] = __builtin_amdgcn_mfma_f32_16x16x32_bf16(
                    a[mi], b[nj], acc[mi][nj], 0, 0, 0);

        if (kt == 15) {                         // fold this ct into running top-2
#pragma unroll
            for (int nj = 0; nj < 4; ++nj) {
                int col = colBase + ct * 128 + wn * 64 + nj * 16 + l15;
                float cc2 = c2[col];
#pragma unroll
                for (int mi = 0; mi < 2; ++mi)
#pragma unroll
                    for (int r = 0; r < 4; ++r) {
                        float sc = fmaf(-2.f, acc[mi][nj][r], cc2);
                        if (sc < bs1[mi][r] || (sc == bs1[mi][r] && col < bi1[mi][r])) {
                            bs2[mi][r] = bs1[mi][r]; bi2[mi][r] = bi1[mi][r];
                            bs1[mi][r] = sc;         bi1[mi][r] = col;
                        } else if (sc < bs2[mi][r] ||
                                   (sc == bs2[mi][r] && col < bi2[mi][r])) {
                            bs2[mi][r] = sc; bi2[mi][r] = col;
                        }
                    }
            }
        }
        if (t < 510) asm volatile("s_waitcnt vmcnt(1)" ::: "memory"); // B(t+1) landed
        else         asm volatile("s_waitcnt vmcnt(0)" ::: "memory");
        __builtin_amdgcn_s_barrier();
        ++bcur; if (bcur >= 3) bcur = 0;
    }

    // final butterfly over the 16 col-lanes, then one part write per row
#pragma unroll
    for (int mi = 0; mi < 2; ++mi)
#pragma unroll
        for (int r = 0; r < 4; ++r) {
            float s1 = bs1[mi][r], s2 = bs2[mi][r];
            int   i1 = bi1[mi][r], i2 = bi2[mi][r];
#pragma unroll
            for (int off = 1; off < 16; off <<= 1) {
                float t1 = __shfl_xor(s1, off, 64); int j1 = __shfl_xor(i1, off, 64);
                float t2 = __shfl_xor(s2, off, 64); int j2 = __shfl_xor(i2, off, 64);
                bool bf = (t1 < s1) || (t1 == s1 && j1 < i1);
                if (bf) {
                    float ns; int ni;
                    if (s1 < t2 || (s1 == t2 && i1 < j2)) { ns = s1; ni = i1; }
                    else                                   { ns = t2; ni = j2; }
                    s1 = t1; i1 = j1; s2 = ns; i2 = ni;
                } else if (t1 < s2 || (t1 == s2 && j1 < i2)) { s2 = t1; i2 = j1; }
            }
            if (l15 == 0) {
                int row = rowBase + wm * 32 + mi * 16 + 4 * lg + r;
                part[(size_t)row * 4 + h * 2 + wn] =
                    make_float4(s1, __int_as_float(i1), s2, __int_as_float(i2));
            }
        }
}

// ---------------------------------------------------------------------------
// Per-row final: 4 span-top2s -> approx min; exact fp32 rescore of all
// candidates within min+1.0 (>14 sigma of bf16 approx error); lexicographic
// (score, idx) min == reference argmin semantics.
// ---------------------------------------------------------------------------
__global__ void k_select(const float4* __restrict__ part,
                         const float* __restrict__ x,
                         const float* __restrict__ cb,
                         const float* __restrict__ c2,
                         float* __restrict__ out_idx_f,
                         int* __restrict__ idx_i,
                         int* __restrict__ used) {
    int wv   = threadIdx.x >> 6;
    int lane = threadIdx.x & 63;
    int row  = blockIdx.x * 4 + wv;
    float4 p;
    if (lane < 4) p = part[(size_t)row * 4 + lane];
    else p = make_float4(INFINITY, __int_as_float(0x7fffffff),
                         INFINITY, __int_as_float(0x7fffffff));
    float s1 = p.x; int i1 = __float_as_int(p.y);
    float s2 = p.z; int i2 = __float_as_int(p.w);
    float gm = s1;
#pragma unroll
    for (int off = 1; off < 64; off <<= 1) gm = fminf(gm, __shfl_xor(gm, off, 64));
    float thresh = gm + 1.0f;
    unsigned long long m1 = __ballot(s1 <= thresh);
    unsigned long long m2 = __ballot(s2 <= thresh);
    float be = INFINITY; int bi = 0x7fffffff;
    const float4* xr = reinterpret_cast<const float4*>(x + (size_t)row * DIM);
    while (m1 | m2) {
        int vi;
        if (m1) { int t = __ffsll(m1) - 1; m1 &= m1 - 1; vi = __shfl(i1, t); }
        else    { int t = __ffsll(m2) - 1; m2 &= m2 - 1; vi = __shfl(i2, t); }
        const float4* cr = reinterpret_cast<const float4*>(cb + (size_t)vi * DIM);
        float d = 0.f;
#pragma unroll
        for (int q = 0; q < 2; ++q) {
            float4 a = xr[q * 64 + lane];
            float4 b = cr[q * 64 + lane];
            d += a.x * b.x + a.y * b.y + a.z * b.z + a.w * b.w;
        }
#pragma unroll
        for (int off = 1; off < 64; off <<= 1) d += __shfl_xor(d, off, 64);
        float se = c2[vi] - 2.f * d;
        if (se < be || (se == be && vi < bi)) { be = se; bi = vi; }
    }
    if (lane == 0) {
        out_idx_f[row] = (float)bi;
        idx_i[row]     = bi;
        used[bi]       = 1;
    }
}

__global__ void k_streak(const int* __restrict__ streak_in,
                         const int* __restrict__ used,
                         float* __restrict__ out) {
    int v = blockIdx.x * 256 + threadIdx.x;
    if (v < VOCAB) out[v] = used[v] ? 0.f : (float)(streak_in[v] + 1);
}

__global__ void k_gather(const float* __restrict__ cb,
                         const int* __restrict__ idx_i,
                         float* __restrict__ out) {
    size_t t  = (size_t)blockIdx.x * 256 + threadIdx.x;
    int    n  = (int)(t >> 7);
    int    d4 = (int)(t & 127);
    reinterpret_cast<float4*>(out)[t] =
        reinterpret_cast<const float4*>(cb + (size_t)idx_i[n] * DIM)[d4];
}

extern "C" void kernel_launch(void* const* d_in, const int* in_sizes, int n_in,
                              void* d_out, int out_size, void* d_ws, size_t ws_size,
                              hipStream_t stream) {
    const float* x      = (const float*)d_in[0];
    const float* cb     = (const float*)d_in[1];
    const int*   streak = (const int*)d_in[2];

    float* out       = (float*)d_out;
    float* out_embed = out;
    float* out_idx   = out + (size_t)N_ROWS * DIM;
    float* out_strk  = out_idx + N_ROWS;

    char* ws = (char*)d_ws;
    unsigned short* xhi  = (unsigned short*)(ws);                 // 16.8 MB
    unsigned short* cbhi = (unsigned short*)(ws + (32u << 20));   // 8.4 MB
    float* c2    = (float*)(ws + (48u << 20));                    // 32 KB
    int*   idx_i = (int*)(ws + (48u << 20) + (1u << 16));         // 64 KB
    int*   used  = (int*)(ws + (48u << 20) + (2u << 16));         // 32 KB
    float4* part = (float4*)(ws + (49u << 20));                   // 1 MB

    hipMemsetAsync(used, 0, VOCAB * sizeof(int), stream);
    k_split_hi<<<(N_ROWS * DIM / 4) / 256, 256, 0, stream>>>(x, xhi, N_ROWS * DIM / 4);
    k_split_cb<<<VOCAB / 4, 256, 0, stream>>>(cb, cbhi, c2);
    k_vq<<<256, 512, 0, stream>>>(xhi, cbhi, c2, part);
    k_select<<<N_ROWS / 4, 256, 0, stream>>>(part, x, cb, c2, out_idx, idx_i, used);
    k_streak<<<VOCAB / 256, 256, 0, stream>>>(streak, used, out_strk);
    k_gather<<<(N_ROWS * DIM / 4) / 256, 256, 0, stream>>>(cb, idx_i, out_embed);
}